// Round 3
// baseline (242.553 us; speedup 1.0000x reference)
//
#include <hip/hip_runtime.h>
#include <hip/hip_fp16.h>

// AdderNet forward:  x[256,1,64,64] -> adder(w1)+BN+ReLU -> adder(w2)+BN+ReLU
//                    -> avgpool -> FC -> out[256,10]
// R8: structural cleanup around the R7 sad16 core.
//   - k_stats1 now writes y1 (raw adder-1 output, fp16) to global; k_layer2's
//     h1-recompute stage (645 instr/thread, 17%) becomes load+BN+quantize
//     (~140 instr; BN folded into quant constants, relu+round via med3 clamp).
//   - k_layer2 LDS 15.9KB -> 13.5KB, launch_bounds(256,8): 32 waves/CU.
//   - k_stats1 split 256 -> 1024 blocks (16-row bands): 16 waves/CU (was 4);
//     activation taps hoisted out of the channel loop (36 ds_reads reused
//     across 16 channels).
//   - d2 LDS read widened to b64 (was b32 hitting even banks only, 2-way).

#define BATCH 256
#define HW 4096

__device__ __forceinline__ uint32_t sad16(uint32_t a, uint32_t b, uint32_t c) {
#if __has_builtin(__builtin_amdgcn_sad_u16)
  return __builtin_amdgcn_sad_u16(a, b, c);
#else
  uint32_t d;
  asm("v_sad_u16 %0, %1, %2, %3" : "=v"(d) : "v"(a), "v"(b), "v"(c));
  return d;
#endif
}

// q(v) = clamp(v*4096 + 4096.5, 4096.5, 65535) truncated; sc4/sf4 carry the
// BN scale/shift pre-multiplied by 4096 (sf4 includes the +4096.5).
__device__ __forceinline__ uint32_t quantq(float f, float sc4, float sf4) {
  float t = fmaf(f, sc4, sf4);
  return (uint32_t)fminf(fmaxf(t, 4096.5f), 65535.f);  // v_med3_f32
}

// ---------------- Kernel 1: layer-1 adder + stats + y1 store ----------------
// grid 1024 = (image b, 16-row quarter). Block 0 also preps w2b (u16 weights
// packed for the sad layout: per (og,c,o) 5 dwords).
__global__ __launch_bounds__(256, 4) void k_stats1(const float* __restrict__ x,
                                                   const float* __restrict__ w1,
                                                   double* __restrict__ s1,
                                                   const float* __restrict__ w2,
                                                   uint32_t* __restrict__ w2b,
                                                   __half* __restrict__ y1) {
  __shared__ float sx[18 * 66];
  __shared__ float red[4 * 16 * 2];
  int blk = blockIdx.x, tid = threadIdx.x;
  int b = blk >> 2, row0 = (blk & 3) * 16;

  if (blk == 0) {  // weight prep: 512 (oc,c) items, 5 dwords each
    for (int i = tid; i < 512; i += 256) {
      int oc = i >> 4, c = i & 15;
      int og = oc >> 3, o = oc & 7;
      const float* wp = w2 + (oc * 16 + c) * 9;
      uint32_t q[9];
#pragma unroll
      for (int t = 0; t < 9; t++) {
        float qf = rintf(fmaf(wp[t], 4096.f, 4096.f));
        q[t] = (uint32_t)fminf(fmaxf(qf, 0.f), 65535.f);
      }
      uint32_t* dst = w2b + ((og * 16 + c) * 8 + o) * 5;
      dst[0] = q[0] | (q[1] << 16);
      dst[1] = q[3] | (q[4] << 16);
      dst[2] = q[6] | (q[7] << 16);
      dst[3] = q[2] | (q[5] << 16);  // vertical pair rows 0,1 (dx=2)
      dst[4] = q[8];                 // single row 2 (zero-extended)
    }
  }

  const float* xb = x + b * HW;
  for (int i = tid; i < 18 * 66; i += 256) {
    int r = i / 66, cc = i - r * 66;
    int ry = row0 + r - 1, rx = cc - 1;
    sx[i] = (ry >= 0 && ry < 64 && rx >= 0 && rx < 64) ? xb[ry * 64 + rx] : 0.f;
  }
  __syncthreads();

  int col = tid & 63, rr = tid >> 6;  // wave rr owns rows rr*4..rr*4+3
  float pa[4][9];
#pragma unroll
  for (int k = 0; k < 4; k++) {
    int rloc = rr * 4 + k;
#pragma unroll
    for (int dy = 0; dy < 3; dy++)
#pragma unroll
      for (int dx = 0; dx < 3; dx++)
        pa[k][dy * 3 + dx] = sx[(rloc + dy) * 66 + col + dx];
  }
  float tsum[16], tsq[16];
#pragma unroll
  for (int c = 0; c < 16; c++) { tsum[c] = 0.f; tsq[c] = 0.f; }
#pragma unroll 1
  for (int c = 0; c < 16; c++) {
    float wv[9];
#pragma unroll
    for (int t = 0; t < 9; t++) wv[t] = w1[c * 9 + t];
    __half* yc = y1 + (((size_t)(b * 16 + c)) << 12);
#pragma unroll
    for (int k = 0; k < 4; k++) {
      float acc = 0.f;
#pragma unroll
      for (int t = 0; t < 9; t++) acc += fabsf(pa[k][t] - wv[t]);
      float v = -acc;
      tsum[c] += v;
      tsq[c] = fmaf(v, v, tsq[c]);
      yc[((row0 + rr * 4 + k) << 6) + col] = __float2half(v);
    }
  }
  int lane = tid & 63, wid = tid >> 6;
#pragma unroll
  for (int c = 0; c < 16; c++) {
    float s = tsum[c], q = tsq[c];
    for (int off = 32; off; off >>= 1) {
      s += __shfl_down(s, off, 64);
      q += __shfl_down(q, off, 64);
    }
    if (lane == 0) { red[(wid * 16 + c) * 2] = s; red[(wid * 16 + c) * 2 + 1] = q; }
  }
  __syncthreads();
  if (tid < 16) {
    float s = red[tid * 2] + red[(16 + tid) * 2] + red[(32 + tid) * 2] + red[(48 + tid) * 2];
    float q = red[tid * 2 + 1] + red[(16 + tid) * 2 + 1] + red[(32 + tid) * 2 + 1] +
              red[(48 + tid) * 2 + 1];
    atomicAdd(&s1[tid], (double)s);
    atomicAdd(&s1[16 + tid], (double)q);
  }
}

// ---------------- Kernel 2: layer 2 (the heavy one) -------------------------
// Block = (image b, 4-row band). Stage: load y1 rows y0-1..y0+4, apply BN1+
// ReLU+u16-quantize into sh (stride 68, col j <-> image col j-1; borders are
// h1=0 -> q=4096). Main loop: per c, 6 LDS b64 + aligns/perms, then 8 o x
// 4 positions x 5 v_sad_u16. Integer-exact accumulation.
__global__ __launch_bounds__(256, 8) void k_layer2(
    const __half* __restrict__ y1, const double* __restrict__ s1,
    const float* __restrict__ g1, const float* __restrict__ b1,
    const uint32_t* __restrict__ w2b, __half* __restrict__ a2,
    double* __restrict__ s2) {
  __shared__ __align__(16) unsigned short sh[16 * 408]; // h1q [c][6 rows][68]
  __shared__ float red[4 * 16];
  __shared__ float sc1s[16], sf1s[16];
  int blk = blockIdx.x;
  int b = blk >> 4, rb = blk & 15;
  int y0 = rb * 4;
  int tid = threadIdx.x;

  if (tid < 16) {  // inline BN1 params, folded into quant constants
    double N = 1048576.0;
    double mean = s1[tid] / N;
    double var = s1[16 + tid] / N - mean * mean;
    float inv = (float)(1.0 / sqrt(var + 1e-5));
    float sc = g1[tid] * inv;
    float sf = b1[tid] - (float)mean * sc;
    sc1s[tid] = sc * 4096.f;
    sf1s[tid] = fmaf(sf, 4096.f, 4096.5f);
  }
  __syncthreads();

  {  // stage h1q tile: thread (c = tid>>4, cg = tid&15) covers LDS cols
     // cg*4..cg*4+3 (image cols cg*4-1..cg*4+2); cg==0 also does cols 64,65.
    int c = tid >> 4, cg = tid & 15;
    float sc4 = sc1s[c], sf4 = sf1s[c];
    const __half* yb = y1 + (((size_t)(b * 16 + c)) << 12);
    unsigned short* shc = sh + c * 408;
#pragma unroll
    for (int row = 0; row < 6; row++) {
      int gr = y0 + row - 1;
      unsigned short* dst = shc + row * 68 + cg * 4;
      if (gr < 0 || gr > 63) {  // whole row is padding: h1=0 -> q=4096
        *reinterpret_cast<uint2*>(dst) = make_uint2(0x10001000u, 0x10001000u);
        if (cg == 0)
          *reinterpret_cast<uint32_t*>(shc + row * 68 + 64) = 0x10001000u;
      } else {
        const __half* yr = yb + (gr << 6);
        int g0 = cg * 4;
        uint32_t A = (cg > 0) ? *reinterpret_cast<const uint32_t*>(yr + g0 - 2) : 0u;
        uint32_t B = *reinterpret_cast<const uint32_t*>(yr + g0);
        uint32_t C = *reinterpret_cast<const uint32_t*>(yr + g0 + 2);
        float fm1 = __half2float(__ushort_as_half((unsigned short)(A >> 16)));
        float f0 = __half2float(__ushort_as_half((unsigned short)(B & 0xffffu)));
        float f1 = __half2float(__ushort_as_half((unsigned short)(B >> 16)));
        float f2 = __half2float(__ushort_as_half((unsigned short)(C & 0xffffu)));
        uint32_t q0 = cg ? quantq(fm1, sc4, sf4) : 4096u;  // col -1 pad
        uint32_t q1 = quantq(f0, sc4, sf4);
        uint32_t q2 = quantq(f1, sc4, sf4);
        uint32_t q3 = quantq(f2, sc4, sf4);
        *reinterpret_cast<uint2*>(dst) = make_uint2(q0 | (q1 << 16), q2 | (q3 << 16));
        if (cg == 0) {  // col 64 = image col 63; col 65 = pad
          float f63 = __half2float(yr[63]);
          *reinterpret_cast<uint32_t*>(shc + row * 68 + 64) =
              quantq(f63, sc4, sf4) | 0x10000000u;
        }
      }
    }
  }
  __syncthreads();

  int lane = tid & 63;
  int wid4 = tid >> 6;
  int wofs = __builtin_amdgcn_readfirstlane(wid4 * 640);  // og weight base
  int r = lane >> 4;          // row within band, 0..3
  int x0 = (lane & 15) << 2;  // 4 output cols per thread
  const unsigned short* shb = sh + r * 68 + x0;

  uint32_t acc[8][4];
#pragma unroll
  for (int o = 0; o < 8; o++)
#pragma unroll
    for (int p = 0; p < 4; p++) acc[o][p] = 0u;

#pragma unroll 1
  for (int c = 0; c < 16; c++) {
    const unsigned short* rp = shb + c * 408;
    uint32_t d0[3], d1[3], d2[3], s01[3], s23[3];
#pragma unroll
    for (int dy = 0; dy < 3; dy++) {
      uint2 t2 = *reinterpret_cast<const uint2*>(rp + dy * 68);      // a0..a3
      uint2 t3 = *reinterpret_cast<const uint2*>(rp + dy * 68 + 4);  // a4..a7*
      d0[dy] = t2.x;
      d1[dy] = t2.y;
      d2[dy] = t3.x;  // (a4,a5); t3.y is row padding slack, unused
      s01[dy] = __builtin_amdgcn_alignbit(d1[dy], d0[dy], 16);  // (a1,a2)
      s23[dy] = __builtin_amdgcn_alignbit(d2[dy], d1[dy], 16);  // (a3,a4)
    }
    // vertical pairs (row0[p+2], row1[p+2]) and singles row2[p+2]
    uint32_t L0 = __builtin_amdgcn_perm(d1[1], d1[0], 0x05040100u);
    uint32_t L1 = __builtin_amdgcn_perm(d1[1], d1[0], 0x07060302u);
    uint32_t L2 = __builtin_amdgcn_perm(d2[1], d2[0], 0x05040100u);
    uint32_t L3 = __builtin_amdgcn_perm(d2[1], d2[0], 0x07060302u);
    uint32_t E0 = d1[2] & 0xffffu, E1 = d1[2] >> 16;
    uint32_t E2 = d2[2] & 0xffffu, E3 = d2[2] >> 16;
    const uint32_t* wc = w2b + wofs + c * 40;  // uniform -> s_load
#pragma unroll
    for (int o = 0; o < 8; o++) {
      uint32_t P0 = wc[o * 5], P1 = wc[o * 5 + 1], P2 = wc[o * 5 + 2];
      uint32_t P3 = wc[o * 5 + 3], P4 = wc[o * 5 + 4];
      acc[o][0] = sad16(d0[0], P0,
                  sad16(d0[1], P1,
                  sad16(d0[2], P2,
                  sad16(L0, P3, sad16(E0, P4, acc[o][0])))));
      acc[o][1] = sad16(s01[0], P0,
                  sad16(s01[1], P1,
                  sad16(s01[2], P2,
                  sad16(L1, P3, sad16(E1, P4, acc[o][1])))));
      acc[o][2] = sad16(d1[0], P0,
                  sad16(d1[1], P1,
                  sad16(d1[2], P2,
                  sad16(L2, P3, sad16(E2, P4, acc[o][2])))));
      acc[o][3] = sad16(s23[0], P0,
                  sad16(s23[1], P1,
                  sad16(s23[2], P2,
                  sad16(L3, P3, sad16(E3, P4, acc[o][3])))));
    }
  }

  // store (negate + rescale) + per-wave stats partials
  const float ksc = -1.f / 4096.f;
  __half* a2b = a2 + ((size_t)b * 32 + wid4 * 8) * HW + (y0 + r) * 64 + x0;
#pragma unroll
  for (int o = 0; o < 8; o++) {
    float f0 = (float)acc[o][0] * ksc, f1 = (float)acc[o][1] * ksc;
    float f2 = (float)acc[o][2] * ksc, f3 = (float)acc[o][3] * ksc;
    __half2 h01 = __floats2half2_rn(f0, f1);
    __half2 h23 = __floats2half2_rn(f2, f3);
    uint2 st = make_uint2(*reinterpret_cast<uint32_t*>(&h01),
                          *reinterpret_cast<uint32_t*>(&h23));
    *reinterpret_cast<uint2*>(a2b + o * HW) = st;
    float2 c0 = __half22float2(h01);  // stats from the stored (rounded) values
    float2 c1 = __half22float2(h23);
    float s = c0.x + c0.y + c1.x + c1.y;
    float q = c0.x * c0.x + c0.y * c0.y + c1.x * c1.x + c1.y * c1.y;
    for (int off = 32; off; off >>= 1) {
      s += __shfl_down(s, off, 64);
      q += __shfl_down(q, off, 64);
    }
    if (lane == 0) { red[wid4 * 16 + o * 2] = s; red[wid4 * 16 + o * 2 + 1] = q; }
  }
  __syncthreads();
  if (tid < 32) {  // wave (tid>>3) owns outputs (tid>>3)*8 + (tid&7)
    float s = red[(tid >> 3) * 16 + (tid & 7) * 2];
    float q = red[(tid >> 3) * 16 + (tid & 7) * 2 + 1];
    atomicAdd(&s2[tid], (double)s);
    atomicAdd(&s2[32 + tid], (double)q);
  }
}

// ---------------- Kernel 3: BN2 (inline params) + ReLU + avgpool + FC -------
__global__ __launch_bounds__(1024) void k_poolfc(const __half* __restrict__ a2,
                                                 const double* __restrict__ s2,
                                                 const float* __restrict__ g2,
                                                 const float* __restrict__ b2,
                                                 const float* __restrict__ fw,
                                                 const float* __restrict__ fb,
                                                 float* __restrict__ out) {
  __shared__ float sc2s[32], sf2s[32];
  __shared__ float poolv[32];
  int b = blockIdx.x, tid = threadIdx.x;
  if (tid < 32) {  // inline BN2 params (block-redundant)
    double N = 1048576.0;
    double mean = s2[tid] / N;
    double var = s2[32 + tid] / N - mean * mean;
    float inv = (float)(1.0 / sqrt(var + 1e-5));
    float sc = g2[tid] * inv;
    sc2s[tid] = sc;
    sf2s[tid] = b2[tid] - (float)mean * sc;
  }
  __syncthreads();
  int o = tid >> 5, part = tid & 31;  // 32 threads per channel
  const uint4* p = (const uint4*)(a2 + ((size_t)b * 32 + o) * HW);
  float s = sc2s[o], f = sf2s[o];
  float acc = 0.f;
#pragma unroll
  for (int i = 0; i < 16; i++) {  // 16 iters * 32 threads * 8 halves = 4096
    uint4 v = p[i * 32 + part];
    float2 f0 = __half22float2(*reinterpret_cast<const __half2*>(&v.x));
    float2 f1 = __half22float2(*reinterpret_cast<const __half2*>(&v.y));
    float2 f2 = __half22float2(*reinterpret_cast<const __half2*>(&v.z));
    float2 f3 = __half22float2(*reinterpret_cast<const __half2*>(&v.w));
    acc += fmaxf(fmaf(f0.x, s, f), 0.f) + fmaxf(fmaf(f0.y, s, f), 0.f) +
           fmaxf(fmaf(f1.x, s, f), 0.f) + fmaxf(fmaf(f1.y, s, f), 0.f) +
           fmaxf(fmaf(f2.x, s, f), 0.f) + fmaxf(fmaf(f2.y, s, f), 0.f) +
           fmaxf(fmaf(f3.x, s, f), 0.f) + fmaxf(fmaf(f3.y, s, f), 0.f);
  }
  acc += __shfl_down(acc, 16, 32);
  acc += __shfl_down(acc, 8, 32);
  acc += __shfl_down(acc, 4, 32);
  acc += __shfl_down(acc, 2, 32);
  acc += __shfl_down(acc, 1, 32);
  if (part == 0) poolv[o] = acc * (1.f / 4096.f);
  __syncthreads();
  if (tid < 10) {
    float rr = fb[tid];
#pragma unroll
    for (int oc = 0; oc < 32; oc++) rr += poolv[oc] * fw[tid * 32 + oc];
    out[b * 10 + tid] = rr;
  }
}

extern "C" void kernel_launch(void* const* d_in, const int* in_sizes, int n_in,
                              void* d_out, int out_size, void* d_ws, size_t ws_size,
                              hipStream_t stream) {
  const float* x   = (const float*)d_in[0];
  const float* w1  = (const float*)d_in[1];
  const float* g1  = (const float*)d_in[2];
  const float* b1  = (const float*)d_in[3];
  const float* w2  = (const float*)d_in[4];
  const float* g2  = (const float*)d_in[5];
  const float* b2  = (const float*)d_in[6];
  const float* fcw = (const float*)d_in[7];
  const float* fcb = (const float*)d_in[8];
  float* out = (float*)d_out;

  char* ws = (char*)d_ws;
  __half* a2 = (__half*)ws;                                // 67,108,864 B
  double* stats = (double*)(ws + 67108864);                // 96 doubles
  double* s1 = stats;                                      // sum[16], sq[16]
  double* s2 = stats + 32;                                 // sum[32], sq[32]
  uint32_t* w2b = (uint32_t*)(ws + 67108864 + 1024);       // 2560 dwords
  __half* y1 = (__half*)(ws + 67108864 + 16384);           // 33,554,432 B

  hipMemsetAsync(stats, 0, 768, stream);
  k_stats1<<<1024, 256, 0, stream>>>(x, w1, s1, w2, w2b, y1);
  k_layer2<<<4096, 256, 0, stream>>>(y1, s1, g1, b1, w2b, a2, s2);
  k_poolfc<<<256, 1024, 0, stream>>>(a2, s2, g2, b2, fcw, fcb, out);
}

// Round 5
// 194.590 us; speedup vs baseline: 1.2465x; 1.2465x over previous
//
#include <hip/hip_runtime.h>
#include <hip/hip_fp16.h>

// AdderNet forward:  x[256,1,64,64] -> adder(w1)+BN+ReLU -> adder(w2)+BN+ReLU
//                    -> avgpool -> FC -> out[256,10]
// R10 = R9 resubmit (container-level failure, no kernel error; audit found
// no OOB/hang; hardened the mqsad asm fallback with early-clobber dst).
//   - h1/w2 quantized u8: q(v)=rint(32v)+48 (offset cancels in |a-w|; the
//     per-channel quantization bias is constant -> absorbed by BN2 mean).
//   - v_mqsad_u32_u8: 4 sliding windows x masked 3-tap SAD + 4 accumulates
//     in ONE VALU instr. Weight ref = (w0,w1,w2,0); mask byte is the 0
//     (weights clamp to >=1, never 0).
//   - aligned b64+b32 LDS reads feed the quads directly: zero shift/perm ops.
//   - 512-thread blocks: 8 waves = 4 og x 2 o-halves, 8-row bands, grid 2048.
//     u8 tile 12.8KB LDS. c-loop software-pipelined 2-deep.

#define BATCH 256
#define HW 4096

typedef unsigned int u32;
typedef unsigned long long u64;
typedef __attribute__((ext_vector_type(4))) unsigned int u32x4;

__device__ __forceinline__ u32x4 mqsad(u64 src, u32 ref, u32x4 acc) {
#if __has_builtin(__builtin_amdgcn_mqsad_u32_u8)
  return __builtin_amdgcn_mqsad_u32_u8(src, ref, acc);
#else
  u32x4 d;
  asm("v_mqsad_u32_u8 %0, %1, %2, %3"
      : "=&v"(d)                       // early-clobber: HW requires dst!=src
      : "v"(src), "v"(ref), "v"(acc));
  return d;
#endif
}

// ---------------- Kernel 1: layer-1 adder + stats + y1 store ----------------
// grid 1024 = (image b, 16-row quarter). Block 0 also preps w2b (u8 weights,
// per (og,c,o): 3 dwords = (w0,w1,w2,0) per tap-row).
__global__ __launch_bounds__(256, 4) void k_stats1(const float* __restrict__ x,
                                                   const float* __restrict__ w1,
                                                   double* __restrict__ s1,
                                                   const float* __restrict__ w2,
                                                   u32* __restrict__ w2b,
                                                   __half* __restrict__ y1) {
  __shared__ float sx[18 * 66];
  __shared__ float red[4 * 16 * 2];
  int blk = blockIdx.x, tid = threadIdx.x;
  int b = blk >> 2, row0 = (blk & 3) * 16;

  if (blk == 0) {  // weight prep: 512 (oc,c) items, 3 dwords each
    for (int i = tid; i < 512; i += 256) {
      int oc = i >> 4, c = i & 15;
      int og = oc >> 3, o = oc & 7;
      const float* wp = w2 + (oc * 16 + c) * 9;
      u32 q[9];
#pragma unroll
      for (int t = 0; t < 9; t++) {
        float qf = rintf(fmaf(wp[t], 32.f, 48.f));
        q[t] = (u32)fminf(fmaxf(qf, 1.f), 255.f);
      }
      u32* dst = w2b + ((og * 16 + c) * 8 + o) * 3;
      dst[0] = q[0] | (q[1] << 8) | (q[2] << 16);
      dst[1] = q[3] | (q[4] << 8) | (q[5] << 16);
      dst[2] = q[6] | (q[7] << 8) | (q[8] << 16);
    }
  }

  const float* xb = x + b * HW;
  for (int i = tid; i < 18 * 66; i += 256) {
    int r = i / 66, cc = i - r * 66;
    int ry = row0 + r - 1, rx = cc - 1;
    sx[i] = (ry >= 0 && ry < 64 && rx >= 0 && rx < 64) ? xb[ry * 64 + rx] : 0.f;
  }
  __syncthreads();

  int col = tid & 63, rr4 = tid >> 6;  // wave rr4 owns rows rr4*4..rr4*4+3
  float pa[4][9];
#pragma unroll
  for (int k = 0; k < 4; k++) {
    int rloc = rr4 * 4 + k;
#pragma unroll
    for (int dy = 0; dy < 3; dy++)
#pragma unroll
      for (int dx = 0; dx < 3; dx++)
        pa[k][dy * 3 + dx] = sx[(rloc + dy) * 66 + col + dx];
  }
  float tsum[16], tsq[16];
#pragma unroll
  for (int c = 0; c < 16; c++) { tsum[c] = 0.f; tsq[c] = 0.f; }
#pragma unroll 1
  for (int c = 0; c < 16; c++) {
    float wv[9];
#pragma unroll
    for (int t = 0; t < 9; t++) wv[t] = w1[c * 9 + t];
    __half* yc = y1 + (((size_t)(b * 16 + c)) << 12);
#pragma unroll
    for (int k = 0; k < 4; k++) {
      float acc = 0.f;
#pragma unroll
      for (int t = 0; t < 9; t++) acc += fabsf(pa[k][t] - wv[t]);
      float v = -acc;
      tsum[c] += v;
      tsq[c] = fmaf(v, v, tsq[c]);
      yc[((row0 + rr4 * 4 + k) << 6) + col] = __float2half(v);
    }
  }
  int lane = tid & 63, wid = tid >> 6;
#pragma unroll
  for (int c = 0; c < 16; c++) {
    float s = tsum[c], q = tsq[c];
    for (int off = 32; off; off >>= 1) {
      s += __shfl_down(s, off, 64);
      q += __shfl_down(q, off, 64);
    }
    if (lane == 0) { red[(wid * 16 + c) * 2] = s; red[(wid * 16 + c) * 2 + 1] = q; }
  }
  __syncthreads();
  if (tid < 16) {
    float s = red[tid * 2] + red[(16 + tid) * 2] + red[(32 + tid) * 2] + red[(48 + tid) * 2];
    float q = red[tid * 2 + 1] + red[(16 + tid) * 2 + 1] + red[(32 + tid) * 2 + 1] +
              red[(48 + tid) * 2 + 1];
    atomicAdd(&s1[tid], (double)s);
    atomicAdd(&s1[16 + tid], (double)q);
  }
}

// ---------------- Kernel 2: layer 2 (the heavy one) -------------------------
// Block = (image b, 8-row band), 512 threads = 8 waves.
// LDS u8 tile: [16 ch][10 rows][stride 80]; storage col s <-> image col s-1
// (col 0 = left pad = 48; cols 65,66 = right pads = 48).
// Wave w: og = w>>1, o-half = w&1 (4 output channels); lane: r = lane>>3
// (band row), x0 = (lane&7)*8 (8 output cols). Per (c,dy): aligned b64+b32
// give both mqsad quads for positions x0..x0+7.
__global__ __launch_bounds__(512, 6) void k_layer2(
    const __half* __restrict__ y1, const double* __restrict__ s1,
    const float* __restrict__ g1, const float* __restrict__ b1,
    const u32* __restrict__ w2b, __half* __restrict__ a2,
    double* __restrict__ s2) {
  __shared__ __align__(16) unsigned char shu[16 * 800];  // 12.8 KB
  __shared__ float red[8 * 8];
  __shared__ float sc1s[16], sf1s[16];
  int blk = blockIdx.x;
  int b = blk >> 3, y0 = (blk & 7) << 3;
  int tid = threadIdx.x;

  if (tid < 16) {  // BN1 params folded into u8 quant constants
    double N = 1048576.0;
    double mean = s1[tid] / N;
    double var = s1[16 + tid] / N - mean * mean;
    float inv = (float)(1.0 / sqrt(var + 1e-5));
    float sc = g1[tid] * inv;
    float sf = b1[tid] - (float)mean * sc;
    sc1s[tid] = sc * 32.f;
    sf1s[tid] = fmaf(sf, 32.f, 48.5f);  // +0.5 for round-half-up via trunc
  }
  __syncthreads();

  // ---- stage: y1 fp16 -> BN -> relu -> u8 quant -> LDS tile --------------
  // 160 row-jobs (16 ch x 10 rows), 8 threads/row (uint4 = 8 halves each).
  // Left-neighbor byte comes from the previous lane via shfl_up (row
  // boundaries land exactly on kq==0, which uses the pad instead).
#pragma unroll 1
  for (int p = 0; p < 3; p++) {
    int jj = p * 512 + tid;
    if (jj < 1280) {
      int rowjob = jj >> 3, kq = jj & 7;
      int ch = rowjob / 10;
      int rr = rowjob - ch * 10;
      int gr = y0 + rr - 1;
      float sc8 = sc1s[ch], sf8 = sf1s[ch];
      u32 B[8];
      if (gr >= 0 && gr < 64) {
        uint4 v = *reinterpret_cast<const uint4*>(
            y1 + (((size_t)(b * 16 + ch)) << 12) + (gr << 6) + (kq << 3));
        const u32* vd = reinterpret_cast<const u32*>(&v);
#pragma unroll
        for (int q = 0; q < 4; q++) {
          float2 f = __half22float2(*reinterpret_cast<const __half2*>(&vd[q]));
          float t0 = fmaf(f.x, sc8, sf8);
          float t1 = fmaf(f.y, sc8, sf8);
          B[q * 2] = (u32)fminf(fmaxf(t0, 48.5f), 255.f);
          B[q * 2 + 1] = (u32)fminf(fmaxf(t1, 48.5f), 255.f);
        }
      } else {
#pragma unroll
        for (int q = 0; q < 8; q++) B[q] = 48u;
      }
      u32 prev = (u32)__shfl_up((int)B[7], 1, 64);
      if (kq == 0) prev = 48u;  // image col -1 pad
      u32 d0 = prev | (B[0] << 8) | (B[1] << 16) | (B[2] << 24);
      u32 d1 = B[3] | (B[4] << 8) | (B[5] << 16) | (B[6] << 24);
      unsigned char* dst = shu + rowjob * 80 + (kq << 3);
      *reinterpret_cast<uint2*>(dst) = make_uint2(d0, d1);
      if (kq == 7)  // storage cols 64..67: image col 63, pads
        *reinterpret_cast<u32*>(dst + 8) = B[7] | 0x30303000u;
    }
  }
  __syncthreads();

  // ---- main loop ---------------------------------------------------------
  int lane = tid & 63;
  int w8 = tid >> 6;  // wave id 0..7
  int og = w8 >> 1, half = w8 & 1;
  int wofs = __builtin_amdgcn_readfirstlane(og * 384 + half * 12);
  const u32* wbase = w2b + wofs;
  int r = lane >> 3;          // band row 0..7
  int x0 = (lane & 7) << 3;   // 8 output cols per thread
  const unsigned char* shb = shu + r * 80 + x0;

  u32x4 acc[4][2];
#pragma unroll
  for (int o = 0; o < 4; o++) {
    acc[o][0] = (u32x4)(0u);
    acc[o][1] = (u32x4)(0u);
  }

  u64 Aa[3], Ab[3];
  u32 Ma[3], Mb[3];
  u32 Wa[12], Wb[12];

#define LOADC(Av, Mv, Wv, cc)                                     \
  do {                                                            \
    const unsigned char* rp_ = shb + (cc) * 800;                  \
    _Pragma("unroll") for (int dy_ = 0; dy_ < 3; dy_++) {         \
      Av[dy_] = *reinterpret_cast<const u64*>(rp_ + dy_ * 80);    \
      Mv[dy_] = *reinterpret_cast<const u32*>(rp_ + dy_ * 80 + 8);\
    }                                                             \
    const u32* wc_ = wbase + (cc) * 24;                           \
    _Pragma("unroll") for (int j_ = 0; j_ < 12; j_++) Wv[j_] = wc_[j_]; \
  } while (0)

#define COMPUTE(Av, Mv, Wv)                                       \
  do {                                                            \
    _Pragma("unroll") for (int dy_ = 0; dy_ < 3; dy_++) {         \
      u64 lo_ = Av[dy_];                                          \
      u64 hi_ = (Av[dy_] >> 32) | ((u64)Mv[dy_] << 32);           \
      _Pragma("unroll") for (int o_ = 0; o_ < 4; o_++) {          \
        u32 wr_ = Wv[o_ * 3 + dy_];                               \
        acc[o_][0] = mqsad(lo_, wr_, acc[o_][0]);                 \
        acc[o_][1] = mqsad(hi_, wr_, acc[o_][1]);                 \
      }                                                           \
    }                                                             \
  } while (0)

  LOADC(Aa, Ma, Wa, 0);
#pragma unroll 1
  for (int c = 0; c < 16; c += 2) {
    LOADC(Ab, Mb, Wb, c + 1);
    COMPUTE(Aa, Ma, Wa);
    if (c < 14) LOADC(Aa, Ma, Wa, c + 2);
    COMPUTE(Ab, Mb, Wb);
  }
#undef LOADC
#undef COMPUTE

  // ---- store (negate + rescale) + per-wave stats partials ----------------
  const float ksc = -1.f / 32.f;
  __half* a2b = a2 + ((size_t)b * 32 + og * 8 + half * 4) * HW + (y0 + r) * 64 + x0;
#pragma unroll
  for (int o = 0; o < 4; o++) {
    float f0 = (float)acc[o][0].x * ksc, f1 = (float)acc[o][0].y * ksc;
    float f2 = (float)acc[o][0].z * ksc, f3 = (float)acc[o][0].w * ksc;
    float f4 = (float)acc[o][1].x * ksc, f5 = (float)acc[o][1].y * ksc;
    float f6 = (float)acc[o][1].z * ksc, f7 = (float)acc[o][1].w * ksc;
    __half2 h01 = __floats2half2_rn(f0, f1);
    __half2 h23 = __floats2half2_rn(f2, f3);
    __half2 h45 = __floats2half2_rn(f4, f5);
    __half2 h67 = __floats2half2_rn(f6, f7);
    uint4 st = make_uint4(*reinterpret_cast<u32*>(&h01), *reinterpret_cast<u32*>(&h23),
                          *reinterpret_cast<u32*>(&h45), *reinterpret_cast<u32*>(&h67));
    *reinterpret_cast<uint4*>(a2b + o * HW) = st;
    float2 c0 = __half22float2(h01), c1 = __half22float2(h23);
    float2 c2 = __half22float2(h45), c3 = __half22float2(h67);
    float s = c0.x + c0.y + c1.x + c1.y + c2.x + c2.y + c3.x + c3.y;
    float q = c0.x * c0.x + c0.y * c0.y + c1.x * c1.x + c1.y * c1.y +
              c2.x * c2.x + c2.y * c2.y + c3.x * c3.x + c3.y * c3.y;
    for (int off = 32; off; off >>= 1) {
      s += __shfl_down(s, off, 64);
      q += __shfl_down(q, off, 64);
    }
    if (lane == 0) { red[w8 * 8 + o * 2] = s; red[w8 * 8 + o * 2 + 1] = q; }
  }
  __syncthreads();
  if (tid < 32) {  // oc -> wave (og*2 + o>>2), slot o&3
    int oc = tid;
    int ww = (oc >> 3) * 2 + ((oc >> 2) & 1);
    int oo = oc & 3;
    float s = red[ww * 8 + oo * 2];
    float q = red[ww * 8 + oo * 2 + 1];
    atomicAdd(&s2[oc], (double)s);
    atomicAdd(&s2[32 + oc], (double)q);
  }
}

// ---------------- Kernel 3: BN2 (inline params) + ReLU + avgpool + FC -------
__global__ __launch_bounds__(1024) void k_poolfc(const __half* __restrict__ a2,
                                                 const double* __restrict__ s2,
                                                 const float* __restrict__ g2,
                                                 const float* __restrict__ b2,
                                                 const float* __restrict__ fw,
                                                 const float* __restrict__ fb,
                                                 float* __restrict__ out) {
  __shared__ float sc2s[32], sf2s[32];
  __shared__ float poolv[32];
  int b = blockIdx.x, tid = threadIdx.x;
  if (tid < 32) {  // inline BN2 params (block-redundant)
    double N = 1048576.0;
    double mean = s2[tid] / N;
    double var = s2[32 + tid] / N - mean * mean;
    float inv = (float)(1.0 / sqrt(var + 1e-5));
    float sc = g2[tid] * inv;
    sc2s[tid] = sc;
    sf2s[tid] = b2[tid] - (float)mean * sc;
  }
  __syncthreads();
  int o = tid >> 5, part = tid & 31;  // 32 threads per channel
  const uint4* p = (const uint4*)(a2 + ((size_t)b * 32 + o) * HW);
  float s = sc2s[o], f = sf2s[o];
  float acc = 0.f;
#pragma unroll
  for (int i = 0; i < 16; i++) {  // 16 iters * 32 threads * 8 halves = 4096
    uint4 v = p[i * 32 + part];
    float2 f0 = __half22float2(*reinterpret_cast<const __half2*>(&v.x));
    float2 f1 = __half22float2(*reinterpret_cast<const __half2*>(&v.y));
    float2 f2 = __half22float2(*reinterpret_cast<const __half2*>(&v.z));
    float2 f3 = __half22float2(*reinterpret_cast<const __half2*>(&v.w));
    acc += fmaxf(fmaf(f0.x, s, f), 0.f) + fmaxf(fmaf(f0.y, s, f), 0.f) +
           fmaxf(fmaf(f1.x, s, f), 0.f) + fmaxf(fmaf(f1.y, s, f), 0.f) +
           fmaxf(fmaf(f2.x, s, f), 0.f) + fmaxf(fmaf(f2.y, s, f), 0.f) +
           fmaxf(fmaf(f3.x, s, f), 0.f) + fmaxf(fmaf(f3.y, s, f), 0.f);
  }
  acc += __shfl_down(acc, 16, 32);
  acc += __shfl_down(acc, 8, 32);
  acc += __shfl_down(acc, 4, 32);
  acc += __shfl_down(acc, 2, 32);
  acc += __shfl_down(acc, 1, 32);
  if (part == 0) poolv[o] = acc * (1.f / 4096.f);
  __syncthreads();
  if (tid < 10) {
    float rr = fb[tid];
#pragma unroll
    for (int oc = 0; oc < 32; oc++) rr += poolv[oc] * fw[tid * 32 + oc];
    out[b * 10 + tid] = rr;
  }
}

extern "C" void kernel_launch(void* const* d_in, const int* in_sizes, int n_in,
                              void* d_out, int out_size, void* d_ws, size_t ws_size,
                              hipStream_t stream) {
  const float* x   = (const float*)d_in[0];
  const float* w1  = (const float*)d_in[1];
  const float* g1  = (const float*)d_in[2];
  const float* b1  = (const float*)d_in[3];
  const float* w2  = (const float*)d_in[4];
  const float* g2  = (const float*)d_in[5];
  const float* b2  = (const float*)d_in[6];
  const float* fcw = (const float*)d_in[7];
  const float* fcb = (const float*)d_in[8];
  float* out = (float*)d_out;

  char* ws = (char*)d_ws;
  __half* a2 = (__half*)ws;                                // 67,108,864 B
  double* stats = (double*)(ws + 67108864);                // 96 doubles
  double* s1 = stats;                                      // sum[16], sq[16]
  double* s2 = stats + 32;                                 // sum[32], sq[32]
  u32* w2b = (u32*)(ws + 67108864 + 1024);                 // 1536 dwords
  __half* y1 = (__half*)(ws + 67108864 + 16384);           // 33,554,432 B

  hipMemsetAsync(stats, 0, 768, stream);
  k_stats1<<<1024, 256, 0, stream>>>(x, w1, s1, w2, w2b, y1);
  k_layer2<<<2048, 512, 0, stream>>>(y1, s1, g1, b1, w2b, a2, s2);
  k_poolfc<<<256, 1024, 0, stream>>>(a2, s2, g2, b2, fcw, fcb, out);
}